// Round 8
// baseline (272.656 us; speedup 1.0000x reference)
//
#include <hip/hip_runtime.h>
#include <hip/hip_bf16.h>
#include <math.h>

#define HID 64
#define DT 0.1f
#define MIN_TAU 0.1f
#define TAU_SCALE 9.9f   // MAX_TAU - MIN_TAU

// Augmented weight rows (bf16), K-major per output row:
//   rows   0..63  : [W_tau(64) | U_tau(3) | b_tau(1) | 0-pad]  -> tau_raw
//   rows  64..127 : [W_h(64)   | U_h(3)   | b_h(1)   | 0-pad]  -> pre
// row stride 104 bf16 = 208 B (16B-aligned; b128 reads 2-way bank alias = free)
#define WSTRIDE 104
#define WROWS   128
#define WELEMS  (WROWS * WSTRIDE)   // 13312 bf16 = 26624 B

typedef __attribute__((ext_vector_type(8))) short bf16x8;
typedef __attribute__((ext_vector_type(4))) float f32x4;

__device__ __forceinline__ short f2bf(float f) {
    union { __hip_bfloat16 b; short s; } c;
    c.b = __float2bfloat16(f);
    return c.s;
}
__device__ __forceinline__ float fast_rcp(float x) { return __builtin_amdgcn_rcpf(x); }
__device__ __forceinline__ float fast_tanh(float x) {
    float e = __expf(2.f * x);
    return fmaf(-2.f, fast_rcp(e + 1.f), 1.f);
}

// ---- kernel 0: convert + pack augmented weights into d_ws ----
__global__ __launch_bounds__(256) void prep_weights(
    const float* __restrict__ W_tau, const float* __restrict__ U_tau,
    const float* __restrict__ b_tau,
    const float* __restrict__ W_h, const float* __restrict__ U_h,
    const float* __restrict__ b_h,
    short* __restrict__ wbf)
{
    const int idx = blockIdx.x * 256 + threadIdx.x;
    if (idx >= WELEMS) return;
    const int row = idx / WSTRIDE;
    const int c = idx - row * WSTRIDE;
    float val = 0.f;
    if (row < 64) {
        const int r = row;
        if (c < 64)       val = W_tau[r * 64 + c];
        else if (c < 67)  val = U_tau[r * 3 + (c - 64)];
        else if (c == 67) val = b_tau[r];
    } else {
        const int r = row - 64;
        if (c < 64)       val = W_h[r * 64 + c];
        else if (c < 67)  val = U_h[r * 3 + (c - 64)];
        else if (c == 67) val = b_h[r];
    }
    wbf[idx] = f2bf(val);
}

// ---- main kernel: 256 thr = 4 waves; wave = 16 positions/tile; tile = 64 pos ----
// GEMM per wave-tile: M=16, N=192 (tau|pre|h-id), K=96 (h|u|1), computed in TWO
// HALVES of 32 channels so only 6 acc tiles (24 regs) are live at once.
// B stays in LDS (r7 proved per-tile ds_reads cost ~4%); reg demand ~110 -> 
// __launch_bounds__(256,4) = 4 waves/SIMD with NO spill (falsifier: FETCH>300MB).
__global__ __launch_bounds__(256, 4) void liquid_mfma_kernel(
    const float* __restrict__ h, const float* __restrict__ u,
    const short* __restrict__ wbf,
    const float* __restrict__ W_out, const float* __restrict__ b_out,
    float* __restrict__ h_out, float* __restrict__ v_out, int ntiles)
{
    __shared__ short wlds[WELEMS];

    const int tid = threadIdx.x;
    {   // stage weights once: 26624 B as 3328 uint4 (b128 writes, conflict-free)
        const uint4* s = (const uint4*)wbf;
        uint4* d = (uint4*)wlds;
        for (int i = tid; i < WELEMS / 8; i += 256) d[i] = s[i];
    }

    const int lane = tid & 63;
    const int col  = lane & 15;
    const int quad = lane >> 4;
    const int wid  = tid >> 6;

    // identity B-fragments (h passthrough, 8 VGPR):
    //   idA: 1.0 at k==col ; idB: 1.0 at k==col+16 (within the MFMA's K=32 window)
    bf16x8 idA, idB;
#pragma unroll
    for (int e = 0; e < 8; ++e) {
        idA[e] = (quad * 8 + e == col)      ? (short)0x3F80 : (short)0;
        idB[e] = (quad * 8 + e == col + 16) ? (short)0x3F80 : (short)0;
    }

    float wo[3][4];
#pragma unroll
    for (int o = 0; o < 3; ++o)
#pragma unroll
        for (int nt = 0; nt < 4; ++nt)
            wo[o][nt] = W_out[o * 64 + nt * 16 + col];
    const float bo_sel = (col == 0) ? b_out[0] : ((col == 1) ? b_out[1] : b_out[2]);

    __syncthreads();   // LDS read-only below: no barriers in the tile loop

    // per-lane LDS base; fragment (nt, ks) = wbase + nt*16*WSTRIDE + ks*32
    const short* wbase = &wlds[col * WSTRIDE + quad * 8];

    const int tstep = gridDim.x;
    int t = blockIdx.x;

    float4 pf0, pf1, pf2, pf3;
    float pu0 = 0.f, pu1 = 0.f, pu2 = 0.f;

#define LOADA(TT)                                                              \
    do {                                                                       \
        const unsigned q_ = (unsigned)(TT) * 64u + (unsigned)(wid * 16 + col); \
        const float* hp_ = h + q_ * 64u + (unsigned)(quad * 8);                \
        pf0 = *(const float4*)hp_;                                             \
        pf1 = *(const float4*)(hp_ + 4);                                       \
        pf2 = *(const float4*)(hp_ + 32);                                      \
        pf3 = *(const float4*)(hp_ + 36);                                      \
        if (quad == 0) {                                                       \
            const float* up_ = u + q_ * 3u;                                    \
            pu0 = up_[0]; pu1 = up_[1]; pu2 = up_[2];                          \
        }                                                                      \
    } while (0)

    if (t < ntiles) LOADA(t);

    for (; t < ntiles; t += tstep) {
        const unsigned q0 = (unsigned)t * 64u + (unsigned)(wid * 16);

        // ---- convert prefetched A to bf16 fragments ----
        bf16x8 af0, af1;
        af0[0] = f2bf(pf0.x); af0[1] = f2bf(pf0.y); af0[2] = f2bf(pf0.z); af0[3] = f2bf(pf0.w);
        af0[4] = f2bf(pf1.x); af0[5] = f2bf(pf1.y); af0[6] = f2bf(pf1.z); af0[7] = f2bf(pf1.w);
        af1[0] = f2bf(pf2.x); af1[1] = f2bf(pf2.y); af1[2] = f2bf(pf2.z); af1[3] = f2bf(pf2.w);
        af1[4] = f2bf(pf3.x); af1[5] = f2bf(pf3.y); af1[6] = f2bf(pf3.z); af1[7] = f2bf(pf3.w);

        bf16x8 af2 = (bf16x8)(short)0;     // k=64..66 -> u, k=67 -> 1.0
        if (quad == 0) {
            af2[0] = f2bf(pu0); af2[1] = f2bf(pu1); af2[2] = f2bf(pu2);
            af2[3] = f2bf(1.0f);
        }

        // ---- issue next tile's loads early (hide under MFMA + epilogue) ----
        const int tn = t + tstep;
        if (tn < ntiles) LOADA(tn);

        float pv[4][3];
#pragma unroll
        for (int r = 0; r < 4; ++r) { pv[r][0] = 0.f; pv[r][1] = 0.f; pv[r][2] = 0.f; }

        // ---- two halves of 32 channels; only 6 acc tiles (24 regs) live ----
#pragma unroll
        for (int H = 0; H < 2; ++H) {
            const f32x4 z = (f32x4){0.f, 0.f, 0.f, 0.f};
            f32x4 aT0 = z, aT1 = z, aP0 = z, aP1 = z, aH0 = z, aH1 = z;

            const short* wT0 = wbase + (H * 2 + 0) * 16 * WSTRIDE;      // tau rows
            const short* wT1 = wbase + (H * 2 + 1) * 16 * WSTRIDE;
            const short* wP0 = wbase + (4 + H * 2) * 16 * WSTRIDE;      // pre rows
            const short* wP1 = wbase + (5 + H * 2) * 16 * WSTRIDE;

            aT0 = __builtin_amdgcn_mfma_f32_16x16x32_bf16(af0, *(const bf16x8*)(wT0),      aT0, 0, 0, 0);
            aT0 = __builtin_amdgcn_mfma_f32_16x16x32_bf16(af1, *(const bf16x8*)(wT0 + 32), aT0, 0, 0, 0);
            aT0 = __builtin_amdgcn_mfma_f32_16x16x32_bf16(af2, *(const bf16x8*)(wT0 + 64), aT0, 0, 0, 0);
            aT1 = __builtin_amdgcn_mfma_f32_16x16x32_bf16(af0, *(const bf16x8*)(wT1),      aT1, 0, 0, 0);
            aT1 = __builtin_amdgcn_mfma_f32_16x16x32_bf16(af1, *(const bf16x8*)(wT1 + 32), aT1, 0, 0, 0);
            aT1 = __builtin_amdgcn_mfma_f32_16x16x32_bf16(af2, *(const bf16x8*)(wT1 + 64), aT1, 0, 0, 0);
            aP0 = __builtin_amdgcn_mfma_f32_16x16x32_bf16(af0, *(const bf16x8*)(wP0),      aP0, 0, 0, 0);
            aP0 = __builtin_amdgcn_mfma_f32_16x16x32_bf16(af1, *(const bf16x8*)(wP0 + 32), aP0, 0, 0, 0);
            aP0 = __builtin_amdgcn_mfma_f32_16x16x32_bf16(af2, *(const bf16x8*)(wP0 + 64), aP0, 0, 0, 0);
            aP1 = __builtin_amdgcn_mfma_f32_16x16x32_bf16(af0, *(const bf16x8*)(wP1),      aP1, 0, 0, 0);
            aP1 = __builtin_amdgcn_mfma_f32_16x16x32_bf16(af1, *(const bf16x8*)(wP1 + 32), aP1, 0, 0, 0);
            aP1 = __builtin_amdgcn_mfma_f32_16x16x32_bf16(af2, *(const bf16x8*)(wP1 + 64), aP1, 0, 0, 0);
            // h passthrough for this half's 32 channels
            const bf16x8 afid = H ? af1 : af0;
            aH0 = __builtin_amdgcn_mfma_f32_16x16x32_bf16(afid, idA, aH0, 0, 0, 0);
            aH1 = __builtin_amdgcn_mfma_f32_16x16x32_bf16(afid, idB, aH1, 0, 0, 0);

            // ---- epilogue for channels H*32 .. H*32+31 ----
#pragma unroll
            for (int r = 0; r < 4; ++r) {
                const unsigned p = q0 + (unsigned)(quad * 4 + r);
#pragma unroll
                for (int j = 0; j < 2; ++j) {
                    const int ntk = H * 2 + j;
                    const float at = j ? aT1[r] : aT0[r];
                    const float ap = j ? aP1[r] : aP0[r];
                    const float hk = j ? aH1[r] : aH0[r];
                    const float sp = fmaxf(at, 0.f) + __logf(1.f + __expf(-fabsf(at)));
                    const float tau = fmaf(sp, TAU_SCALE, MIN_TAU);
                    const float f = fast_rcp(1.f + __expf(-ap));
                    const float hnew = fmaf(DT, f - hk * fast_rcp(tau), hk);
                    h_out[p * 64u + (unsigned)(ntk * 16 + col)] = hnew;
                    pv[r][0] = fmaf(hnew, wo[0][ntk], pv[r][0]);
                    pv[r][1] = fmaf(hnew, wo[1][ntk], pv[r][1]);
                    pv[r][2] = fmaf(hnew, wo[2][ntk], pv[r][2]);
                }
            }
        }

        // ---- v reduce (over col within each quad) + lane-select store ----
#pragma unroll
        for (int r = 0; r < 4; ++r) {
            const unsigned p = q0 + (unsigned)(quad * 4 + r);
            float pv0 = pv[r][0], pv1 = pv[r][1], pv2 = pv[r][2];
#pragma unroll
            for (int s = 1; s < 16; s <<= 1) {
                pv0 += __shfl_xor(pv0, s, 64);
                pv1 += __shfl_xor(pv1, s, 64);
                pv2 += __shfl_xor(pv2, s, 64);
            }
            const float pvs = (col == 0) ? pv0 : ((col == 1) ? pv1 : pv2);
            if (col < 3)
                v_out[p * 3u + (unsigned)col] = fast_tanh(pvs + bo_sel);
        }
    }
#undef LOADA
}

extern "C" void kernel_launch(void* const* d_in, const int* in_sizes, int n_in,
                              void* d_out, int out_size, void* d_ws, size_t ws_size,
                              hipStream_t stream) {
    const float* h     = (const float*)d_in[0];
    const float* u     = (const float*)d_in[1];
    const float* W_h   = (const float*)d_in[2];
    const float* U_h   = (const float*)d_in[3];
    const float* b_h   = (const float*)d_in[4];
    const float* W_tau = (const float*)d_in[5];
    const float* U_tau = (const float*)d_in[6];
    const float* b_tau = (const float*)d_in[7];
    const float* W_out = (const float*)d_in[8];
    const float* b_out = (const float*)d_in[9];

    const int total = in_sizes[0] / HID;   // B*N positions (1048576)
    float* h_out = (float*)d_out;
    float* v_out = h_out + (size_t)total * HID;

    short* wbf = (short*)d_ws;   // 26624 B of scratch

    prep_weights<<<(WELEMS + 255) / 256, 256, 0, stream>>>(
        W_tau, U_tau, b_tau, W_h, U_h, b_h, wbf);

    const int ntiles = total / 64;   // 64 positions per block-tile
    const int grid = 1024;           // 4 resident blocks/CU, 16 tiles each
    liquid_mfma_kernel<<<grid, 256, 0, stream>>>(
        h, u, wbf, W_out, b_out, h_out, v_out, ntiles);
}

// Round 9
// 132.481 us; speedup vs baseline: 2.0581x; 2.0581x over previous
//
#include <hip/hip_runtime.h>
#include <hip/hip_bf16.h>
#include <math.h>

#define HID 64
#define DT 0.1f
#define MIN_TAU 0.1f
#define TAU_SCALE 9.9f   // MAX_TAU - MIN_TAU

// Augmented weight rows (bf16), K-major per output row:
//   rows   0..63  : [W_tau(64) | U_tau(3) | b_tau(1) | 0-pad]  -> tau_raw
//   rows  64..127 : [W_h(64)   | U_h(3)   | b_h(1)   | 0-pad]  -> pre
// row stride 104 bf16 = 208 B (16B-aligned; b128 reads 2-way bank alias = free)
#define WSTRIDE 104
#define WROWS   128
#define WELEMS  (WROWS * WSTRIDE)   // 13312 bf16 = 26624 B

typedef __attribute__((ext_vector_type(8))) short bf16x8;
typedef __attribute__((ext_vector_type(4))) float f32x4;

__device__ __forceinline__ short f2bf(float f) {
    union { __hip_bfloat16 b; short s; } c;
    c.b = __float2bfloat16(f);
    return c.s;
}
__device__ __forceinline__ float fast_rcp(float x) { return __builtin_amdgcn_rcpf(x); }
__device__ __forceinline__ float fast_tanh(float x) {
    float e = __expf(2.f * x);
    return fmaf(-2.f, fast_rcp(e + 1.f), 1.f);
}

// ---- kernel 0: convert + pack augmented weights into d_ws ----
__global__ __launch_bounds__(256) void prep_weights(
    const float* __restrict__ W_tau, const float* __restrict__ U_tau,
    const float* __restrict__ b_tau,
    const float* __restrict__ W_h, const float* __restrict__ U_h,
    const float* __restrict__ b_h,
    short* __restrict__ wbf)
{
    const int idx = blockIdx.x * 256 + threadIdx.x;
    if (idx >= WELEMS) return;
    const int row = idx / WSTRIDE;
    const int c = idx - row * WSTRIDE;
    float val = 0.f;
    if (row < 64) {
        const int r = row;
        if (c < 64)       val = W_tau[r * 64 + c];
        else if (c < 67)  val = U_tau[r * 3 + (c - 64)];
        else if (c == 67) val = b_tau[r];
    } else {
        const int r = row - 64;
        if (c < 64)       val = W_h[r * 64 + c];
        else if (c < 67)  val = U_h[r * 3 + (c - 64)];
        else if (c == 67) val = b_h[r];
    }
    wbf[idx] = f2bf(val);
}

// ---- main kernel: 256 thr = 4 waves; wave = 16 positions/tile; tile = 64 pos ----
// GEMM per wave-tile: M=16, N=192 (tau|pre|h-id), K=96 (h|u|1), in TWO HALVES of
// 32 channels (6 live acc tiles = 24 regs), sched_barrier(0) between halves so
// the scheduler cannot fuse both halves' live ranges.
// Natural demand ~150 regs -> __launch_bounds__(256,3) cap ~170: NO SPILL.
// (History: caps 128 (r4, r8) and 170-with-monolithic-acc (r5) spilled -> FETCH
//  exploded to 0.5-1 GB. Falsifier this round: FETCH > 300 MB = spilled.)
__global__ __launch_bounds__(256, 3) void liquid_mfma_kernel(
    const float* __restrict__ h, const float* __restrict__ u,
    const short* __restrict__ wbf,
    const float* __restrict__ W_out, const float* __restrict__ b_out,
    float* __restrict__ h_out, float* __restrict__ v_out, int ntiles)
{
    __shared__ short wlds[WELEMS];

    const int tid = threadIdx.x;
    {   // stage weights once: 26624 B as 3328 uint4 (b128 writes, conflict-free)
        const uint4* s = (const uint4*)wbf;
        uint4* d = (uint4*)wlds;
        for (int i = tid; i < WELEMS / 8; i += 256) d[i] = s[i];
    }

    const int lane = tid & 63;
    const int col  = lane & 15;
    const int quad = lane >> 4;
    const int wid  = tid >> 6;

    // identity B-fragments (h passthrough, 8 VGPR):
    //   idA: 1.0 at k==col ; idB: 1.0 at k==col+16 (within the MFMA's K=32 window)
    bf16x8 idA, idB;
#pragma unroll
    for (int e = 0; e < 8; ++e) {
        idA[e] = (quad * 8 + e == col)      ? (short)0x3F80 : (short)0;
        idB[e] = (quad * 8 + e == col + 16) ? (short)0x3F80 : (short)0;
    }

    float wo[3][4];
#pragma unroll
    for (int o = 0; o < 3; ++o)
#pragma unroll
        for (int nt = 0; nt < 4; ++nt)
            wo[o][nt] = W_out[o * 64 + nt * 16 + col];
    const float bo_sel = (col == 0) ? b_out[0] : ((col == 1) ? b_out[1] : b_out[2]);

    __syncthreads();   // LDS read-only below: no barriers in the tile loop

    // per-lane LDS base; fragment (nt, ks) = wbase + nt*16*WSTRIDE + ks*32
    const short* wbase = &wlds[col * WSTRIDE + quad * 8];

    const int tstep = gridDim.x;
    int t = blockIdx.x;

    float4 pf0, pf1, pf2, pf3;
    float pu0 = 0.f, pu1 = 0.f, pu2 = 0.f;

#define LOADA(TT)                                                              \
    do {                                                                       \
        const unsigned q_ = (unsigned)(TT) * 64u + (unsigned)(wid * 16 + col); \
        const float* hp_ = h + q_ * 64u + (unsigned)(quad * 8);                \
        pf0 = *(const float4*)hp_;                                             \
        pf1 = *(const float4*)(hp_ + 4);                                       \
        pf2 = *(const float4*)(hp_ + 32);                                      \
        pf3 = *(const float4*)(hp_ + 36);                                      \
        if (quad == 0) {                                                       \
            const float* up_ = u + q_ * 3u;                                    \
            pu0 = up_[0]; pu1 = up_[1]; pu2 = up_[2];                          \
        }                                                                      \
    } while (0)

    if (t < ntiles) LOADA(t);

    for (; t < ntiles; t += tstep) {
        const unsigned q0 = (unsigned)t * 64u + (unsigned)(wid * 16);

        // ---- convert prefetched A to bf16 fragments ----
        bf16x8 af0, af1;
        af0[0] = f2bf(pf0.x); af0[1] = f2bf(pf0.y); af0[2] = f2bf(pf0.z); af0[3] = f2bf(pf0.w);
        af0[4] = f2bf(pf1.x); af0[5] = f2bf(pf1.y); af0[6] = f2bf(pf1.z); af0[7] = f2bf(pf1.w);
        af1[0] = f2bf(pf2.x); af1[1] = f2bf(pf2.y); af1[2] = f2bf(pf2.z); af1[3] = f2bf(pf2.w);
        af1[4] = f2bf(pf3.x); af1[5] = f2bf(pf3.y); af1[6] = f2bf(pf3.z); af1[7] = f2bf(pf3.w);

        bf16x8 af2 = (bf16x8)(short)0;     // k=64..66 -> u, k=67 -> 1.0
        if (quad == 0) {
            af2[0] = f2bf(pu0); af2[1] = f2bf(pu1); af2[2] = f2bf(pu2);
            af2[3] = f2bf(1.0f);
        }

        // ---- issue next tile's loads early (hide under MFMA + epilogue) ----
        const int tn = t + tstep;
        if (tn < ntiles) LOADA(tn);

        float pv[4][3];
#pragma unroll
        for (int r = 0; r < 4; ++r) { pv[r][0] = 0.f; pv[r][1] = 0.f; pv[r][2] = 0.f; }

        // ---- two halves of 32 channels; only 6 acc tiles (24 regs) live ----
#pragma unroll
        for (int H = 0; H < 2; ++H) {
            const f32x4 z = (f32x4){0.f, 0.f, 0.f, 0.f};
            f32x4 aT0 = z, aT1 = z, aP0 = z, aP1 = z, aH0 = z, aH1 = z;

            const short* wT0 = wbase + (H * 2 + 0) * 16 * WSTRIDE;      // tau rows
            const short* wT1 = wbase + (H * 2 + 1) * 16 * WSTRIDE;
            const short* wP0 = wbase + (4 + H * 2) * 16 * WSTRIDE;      // pre rows
            const short* wP1 = wbase + (5 + H * 2) * 16 * WSTRIDE;

            aT0 = __builtin_amdgcn_mfma_f32_16x16x32_bf16(af0, *(const bf16x8*)(wT0),      aT0, 0, 0, 0);
            aT0 = __builtin_amdgcn_mfma_f32_16x16x32_bf16(af1, *(const bf16x8*)(wT0 + 32), aT0, 0, 0, 0);
            aT0 = __builtin_amdgcn_mfma_f32_16x16x32_bf16(af2, *(const bf16x8*)(wT0 + 64), aT0, 0, 0, 0);
            aT1 = __builtin_amdgcn_mfma_f32_16x16x32_bf16(af0, *(const bf16x8*)(wT1),      aT1, 0, 0, 0);
            aT1 = __builtin_amdgcn_mfma_f32_16x16x32_bf16(af1, *(const bf16x8*)(wT1 + 32), aT1, 0, 0, 0);
            aT1 = __builtin_amdgcn_mfma_f32_16x16x32_bf16(af2, *(const bf16x8*)(wT1 + 64), aT1, 0, 0, 0);
            aP0 = __builtin_amdgcn_mfma_f32_16x16x32_bf16(af0, *(const bf16x8*)(wP0),      aP0, 0, 0, 0);
            aP0 = __builtin_amdgcn_mfma_f32_16x16x32_bf16(af1, *(const bf16x8*)(wP0 + 32), aP0, 0, 0, 0);
            aP0 = __builtin_amdgcn_mfma_f32_16x16x32_bf16(af2, *(const bf16x8*)(wP0 + 64), aP0, 0, 0, 0);
            aP1 = __builtin_amdgcn_mfma_f32_16x16x32_bf16(af0, *(const bf16x8*)(wP1),      aP1, 0, 0, 0);
            aP1 = __builtin_amdgcn_mfma_f32_16x16x32_bf16(af1, *(const bf16x8*)(wP1 + 32), aP1, 0, 0, 0);
            aP1 = __builtin_amdgcn_mfma_f32_16x16x32_bf16(af2, *(const bf16x8*)(wP1 + 64), aP1, 0, 0, 0);
            // h passthrough for this half's 32 channels
            const bf16x8 afid = H ? af1 : af0;
            aH0 = __builtin_amdgcn_mfma_f32_16x16x32_bf16(afid, idA, aH0, 0, 0, 0);
            aH1 = __builtin_amdgcn_mfma_f32_16x16x32_bf16(afid, idB, aH1, 0, 0, 0);

            // ---- epilogue for channels H*32 .. H*32+31 ----
#pragma unroll
            for (int r = 0; r < 4; ++r) {
                const unsigned p = q0 + (unsigned)(quad * 4 + r);
#pragma unroll
                for (int j = 0; j < 2; ++j) {
                    const int ntk = H * 2 + j;
                    const float at = j ? aT1[r] : aT0[r];
                    const float ap = j ? aP1[r] : aP0[r];
                    const float hk = j ? aH1[r] : aH0[r];
                    const float sp = fmaxf(at, 0.f) + __logf(1.f + __expf(-fabsf(at)));
                    // DT/tau = 0.1/(0.1 + 9.9*sp) = 1/(1 + 99*sp)
                    const float g = fast_rcp(fmaf(99.f, sp, 1.f));
                    const float f = fast_rcp(1.f + __expf(-ap));
                    const float hnew = fmaf(-hk, g, fmaf(DT, f, hk));
                    h_out[p * 64u + (unsigned)(ntk * 16 + col)] = hnew;
                    pv[r][0] = fmaf(hnew, wo[0][ntk], pv[r][0]);
                    pv[r][1] = fmaf(hnew, wo[1][ntk], pv[r][1]);
                    pv[r][2] = fmaf(hnew, wo[2][ntk], pv[r][2]);
                }
            }
            // keep the two halves' live ranges disjoint (reg-pressure fence)
            __builtin_amdgcn_sched_barrier(0);
        }

        // ---- v reduce (over col within each quad) + lane-select store ----
#pragma unroll
        for (int r = 0; r < 4; ++r) {
            const unsigned p = q0 + (unsigned)(quad * 4 + r);
            float pv0 = pv[r][0], pv1 = pv[r][1], pv2 = pv[r][2];
#pragma unroll
            for (int s = 1; s < 16; s <<= 1) {
                pv0 += __shfl_xor(pv0, s, 64);
                pv1 += __shfl_xor(pv1, s, 64);
                pv2 += __shfl_xor(pv2, s, 64);
            }
            const float pvs = (col == 0) ? pv0 : ((col == 1) ? pv1 : pv2);
            if (col < 3)
                v_out[p * 3u + (unsigned)col] = fast_tanh(pvs + bo_sel);
        }
    }
#undef LOADA
}

extern "C" void kernel_launch(void* const* d_in, const int* in_sizes, int n_in,
                              void* d_out, int out_size, void* d_ws, size_t ws_size,
                              hipStream_t stream) {
    const float* h     = (const float*)d_in[0];
    const float* u     = (const float*)d_in[1];
    const float* W_h   = (const float*)d_in[2];
    const float* U_h   = (const float*)d_in[3];
    const float* b_h   = (const float*)d_in[4];
    const float* W_tau = (const float*)d_in[5];
    const float* U_tau = (const float*)d_in[6];
    const float* b_tau = (const float*)d_in[7];
    const float* W_out = (const float*)d_in[8];
    const float* b_out = (const float*)d_in[9];

    const int total = in_sizes[0] / HID;   // B*N positions (1048576)
    float* h_out = (float*)d_out;
    float* v_out = h_out + (size_t)total * HID;

    short* wbf = (short*)d_ws;   // 26624 B of scratch

    prep_weights<<<(WELEMS + 255) / 256, 256, 0, stream>>>(
        W_tau, U_tau, b_tau, W_h, U_h, b_h, wbf);

    const int ntiles = total / 64;   // 64 positions per block-tile
    // grid 768 = one balanced round at 3 blocks/CU (launch_bounds(256,3));
    // 21-22 tiles per block amortize the weight staging.
    const int grid = 768;
    liquid_mfma_kernel<<<grid, 256, 0, stream>>>(
        h, u, wbf, W_out, b_out, h_out, v_out, ntiles);
}

// Round 10
// 128.798 us; speedup vs baseline: 2.1169x; 1.0286x over previous
//
#include <hip/hip_runtime.h>
#include <hip/hip_bf16.h>
#include <math.h>

#define HID 64
#define DT 0.1f
#define MIN_TAU 0.1f
#define TAU_SCALE 9.9f   // MAX_TAU - MIN_TAU

// Augmented weight rows (bf16), K-major per output row:
//   rows   0..63  : [W_tau(64) | U_tau(3) | b_tau(1) | 0-pad]  -> tau_raw
//   rows  64..127 : [W_h(64)   | U_h(3)   | b_h(1)   | 0-pad]  -> pre
// row stride 104 bf16 = 208 B (16B-aligned; b128 reads 2-way bank alias = free)
#define WSTRIDE 104
#define WROWS   128
#define WELEMS  (WROWS * WSTRIDE)   // 13312 bf16 = 26624 B

typedef __attribute__((ext_vector_type(8))) short bf16x8;
typedef __attribute__((ext_vector_type(4))) float f32x4;

__device__ __forceinline__ short f2bf(float f) {
    union { __hip_bfloat16 b; short s; } c;
    c.b = __float2bfloat16(f);
    return c.s;
}
__device__ __forceinline__ float fast_rcp(float x) { return __builtin_amdgcn_rcpf(x); }
__device__ __forceinline__ float fast_tanh(float x) {
    float e = __expf(2.f * x);
    return fmaf(-2.f, fast_rcp(e + 1.f), 1.f);
}

// DPP rotate-add within each 16-lane row (quad): pure VALU, zero LDS-pipe usage.
// row_ror:N ctrl = 0x120 + N. After steps 1,2,4,8 every lane holds the row sum.
template <int N>
__device__ __forceinline__ float dpp_row_radd(float x) {
    const int yi = __builtin_amdgcn_update_dpp(
        0, __builtin_bit_cast(int, x), 0x120 + N, 0xf, 0xf, true);
    return x + __builtin_bit_cast(float, yi);
}
__device__ __forceinline__ float row16_sum(float x) {
    x = dpp_row_radd<1>(x);
    x = dpp_row_radd<2>(x);
    x = dpp_row_radd<4>(x);
    x = dpp_row_radd<8>(x);
    return x;
}

// ---- kernel 0: convert + pack augmented weights into d_ws ----
__global__ __launch_bounds__(256) void prep_weights(
    const float* __restrict__ W_tau, const float* __restrict__ U_tau,
    const float* __restrict__ b_tau,
    const float* __restrict__ W_h, const float* __restrict__ U_h,
    const float* __restrict__ b_h,
    short* __restrict__ wbf)
{
    const int idx = blockIdx.x * 256 + threadIdx.x;
    if (idx >= WELEMS) return;
    const int row = idx / WSTRIDE;
    const int c = idx - row * WSTRIDE;
    float val = 0.f;
    if (row < 64) {
        const int r = row;
        if (c < 64)       val = W_tau[r * 64 + c];
        else if (c < 67)  val = U_tau[r * 3 + (c - 64)];
        else if (c == 67) val = b_tau[r];
    } else {
        const int r = row - 64;
        if (c < 64)       val = W_h[r * 64 + c];
        else if (c < 67)  val = U_h[r * 3 + (c - 64)];
        else if (c == 67) val = b_h[r];
    }
    wbf[idx] = f2bf(val);
}

// ---- main kernel: 256 thr = 4 waves; wave = 16 positions/tile; tile = 64 pos ----
// GEMM per wave-tile: M=16, N=192 (tau|pre|h-id), K=96 (h|u|1), in TWO HALVES of
// 32 channels (6 live acc tiles = 24 regs), sched_barrier(0) between halves so
// the scheduler cannot fuse both halves' live ranges.
// Natural demand ~150 regs -> __launch_bounds__(256,3) cap ~170: NO SPILL
// (falsifier: FETCH > 300 MB = spilled; r9 proved this config clean).
// v-reduce uses DPP row_ror rotate-adds (VALU) instead of __shfl_xor (LDS pipe):
// removes ~288 cyc/wave-tile of serialized LDS traffic (~31 us/CU chip-wide).
__global__ __launch_bounds__(256, 3) void liquid_mfma_kernel(
    const float* __restrict__ h, const float* __restrict__ u,
    const short* __restrict__ wbf,
    const float* __restrict__ W_out, const float* __restrict__ b_out,
    float* __restrict__ h_out, float* __restrict__ v_out, int ntiles)
{
    __shared__ short wlds[WELEMS];

    const int tid = threadIdx.x;
    {   // stage weights once: 26624 B as 3328 uint4 (b128 writes, conflict-free)
        const uint4* s = (const uint4*)wbf;
        uint4* d = (uint4*)wlds;
        for (int i = tid; i < WELEMS / 8; i += 256) d[i] = s[i];
    }

    const int lane = tid & 63;
    const int col  = lane & 15;
    const int quad = lane >> 4;
    const int wid  = tid >> 6;

    // identity B-fragments (h passthrough, 8 VGPR):
    //   idA: 1.0 at k==col ; idB: 1.0 at k==col+16 (within the MFMA's K=32 window)
    bf16x8 idA, idB;
#pragma unroll
    for (int e = 0; e < 8; ++e) {
        idA[e] = (quad * 8 + e == col)      ? (short)0x3F80 : (short)0;
        idB[e] = (quad * 8 + e == col + 16) ? (short)0x3F80 : (short)0;
    }

    float wo[3][4];
#pragma unroll
    for (int o = 0; o < 3; ++o)
#pragma unroll
        for (int nt = 0; nt < 4; ++nt)
            wo[o][nt] = W_out[o * 64 + nt * 16 + col];
    const float bo_sel = (col == 0) ? b_out[0] : ((col == 1) ? b_out[1] : b_out[2]);

    __syncthreads();   // LDS read-only below: no barriers in the tile loop

    // per-lane LDS base; fragment (nt, ks) = wbase + nt*16*WSTRIDE + ks*32
    const short* wbase = &wlds[col * WSTRIDE + quad * 8];

    const int tstep = gridDim.x;
    int t = blockIdx.x;

    float4 pf0, pf1, pf2, pf3;
    float pu0 = 0.f, pu1 = 0.f, pu2 = 0.f;

#define LOADA(TT)                                                              \
    do {                                                                       \
        const unsigned q_ = (unsigned)(TT) * 64u + (unsigned)(wid * 16 + col); \
        const float* hp_ = h + q_ * 64u + (unsigned)(quad * 8);                \
        pf0 = *(const float4*)hp_;                                             \
        pf1 = *(const float4*)(hp_ + 4);                                       \
        pf2 = *(const float4*)(hp_ + 32);                                      \
        pf3 = *(const float4*)(hp_ + 36);                                      \
        if (quad == 0) {                                                       \
            const float* up_ = u + q_ * 3u;                                    \
            pu0 = up_[0]; pu1 = up_[1]; pu2 = up_[2];                          \
        }                                                                      \
    } while (0)

    if (t < ntiles) LOADA(t);

    for (; t < ntiles; t += tstep) {
        const unsigned q0 = (unsigned)t * 64u + (unsigned)(wid * 16);

        // ---- convert prefetched A to bf16 fragments ----
        bf16x8 af0, af1;
        af0[0] = f2bf(pf0.x); af0[1] = f2bf(pf0.y); af0[2] = f2bf(pf0.z); af0[3] = f2bf(pf0.w);
        af0[4] = f2bf(pf1.x); af0[5] = f2bf(pf1.y); af0[6] = f2bf(pf1.z); af0[7] = f2bf(pf1.w);
        af1[0] = f2bf(pf2.x); af1[1] = f2bf(pf2.y); af1[2] = f2bf(pf2.z); af1[3] = f2bf(pf2.w);
        af1[4] = f2bf(pf3.x); af1[5] = f2bf(pf3.y); af1[6] = f2bf(pf3.z); af1[7] = f2bf(pf3.w);

        bf16x8 af2 = (bf16x8)(short)0;     // k=64..66 -> u, k=67 -> 1.0
        if (quad == 0) {
            af2[0] = f2bf(pu0); af2[1] = f2bf(pu1); af2[2] = f2bf(pu2);
            af2[3] = f2bf(1.0f);
        }

        // ---- issue next tile's loads early (hide under MFMA + epilogue) ----
        const int tn = t + tstep;
        if (tn < ntiles) LOADA(tn);

        float pv[4][3];
#pragma unroll
        for (int r = 0; r < 4; ++r) { pv[r][0] = 0.f; pv[r][1] = 0.f; pv[r][2] = 0.f; }

        // ---- two halves of 32 channels; only 6 acc tiles (24 regs) live ----
#pragma unroll
        for (int H = 0; H < 2; ++H) {
            const f32x4 z = (f32x4){0.f, 0.f, 0.f, 0.f};
            f32x4 aT0 = z, aT1 = z, aP0 = z, aP1 = z, aH0 = z, aH1 = z;

            const short* wT0 = wbase + (H * 2 + 0) * 16 * WSTRIDE;      // tau rows
            const short* wT1 = wbase + (H * 2 + 1) * 16 * WSTRIDE;
            const short* wP0 = wbase + (4 + H * 2) * 16 * WSTRIDE;      // pre rows
            const short* wP1 = wbase + (5 + H * 2) * 16 * WSTRIDE;

            aT0 = __builtin_amdgcn_mfma_f32_16x16x32_bf16(af0, *(const bf16x8*)(wT0),      aT0, 0, 0, 0);
            aT0 = __builtin_amdgcn_mfma_f32_16x16x32_bf16(af1, *(const bf16x8*)(wT0 + 32), aT0, 0, 0, 0);
            aT0 = __builtin_amdgcn_mfma_f32_16x16x32_bf16(af2, *(const bf16x8*)(wT0 + 64), aT0, 0, 0, 0);
            aT1 = __builtin_amdgcn_mfma_f32_16x16x32_bf16(af0, *(const bf16x8*)(wT1),      aT1, 0, 0, 0);
            aT1 = __builtin_amdgcn_mfma_f32_16x16x32_bf16(af1, *(const bf16x8*)(wT1 + 32), aT1, 0, 0, 0);
            aT1 = __builtin_amdgcn_mfma_f32_16x16x32_bf16(af2, *(const bf16x8*)(wT1 + 64), aT1, 0, 0, 0);
            aP0 = __builtin_amdgcn_mfma_f32_16x16x32_bf16(af0, *(const bf16x8*)(wP0),      aP0, 0, 0, 0);
            aP0 = __builtin_amdgcn_mfma_f32_16x16x32_bf16(af1, *(const bf16x8*)(wP0 + 32), aP0, 0, 0, 0);
            aP0 = __builtin_amdgcn_mfma_f32_16x16x32_bf16(af2, *(const bf16x8*)(wP0 + 64), aP0, 0, 0, 0);
            aP1 = __builtin_amdgcn_mfma_f32_16x16x32_bf16(af0, *(const bf16x8*)(wP1),      aP1, 0, 0, 0);
            aP1 = __builtin_amdgcn_mfma_f32_16x16x32_bf16(af1, *(const bf16x8*)(wP1 + 32), aP1, 0, 0, 0);
            aP1 = __builtin_amdgcn_mfma_f32_16x16x32_bf16(af2, *(const bf16x8*)(wP1 + 64), aP1, 0, 0, 0);
            // h passthrough for this half's 32 channels
            const bf16x8 afid = H ? af1 : af0;
            aH0 = __builtin_amdgcn_mfma_f32_16x16x32_bf16(afid, idA, aH0, 0, 0, 0);
            aH1 = __builtin_amdgcn_mfma_f32_16x16x32_bf16(afid, idB, aH1, 0, 0, 0);

            // ---- epilogue for channels H*32 .. H*32+31 ----
#pragma unroll
            for (int r = 0; r < 4; ++r) {
                const unsigned p = q0 + (unsigned)(quad * 4 + r);
#pragma unroll
                for (int j = 0; j < 2; ++j) {
                    const int ntk = H * 2 + j;
                    const float at = j ? aT1[r] : aT0[r];
                    const float ap = j ? aP1[r] : aP0[r];
                    const float hk = j ? aH1[r] : aH0[r];
                    const float sp = fmaxf(at, 0.f) + __logf(1.f + __expf(-fabsf(at)));
                    // DT/tau = 0.1/(0.1 + 9.9*sp) = 1/(1 + 99*sp)
                    const float g = fast_rcp(fmaf(99.f, sp, 1.f));
                    const float f = fast_rcp(1.f + __expf(-ap));
                    const float hnew = fmaf(-hk, g, fmaf(DT, f, hk));
                    h_out[p * 64u + (unsigned)(ntk * 16 + col)] = hnew;
                    pv[r][0] = fmaf(hnew, wo[0][ntk], pv[r][0]);
                    pv[r][1] = fmaf(hnew, wo[1][ntk], pv[r][1]);
                    pv[r][2] = fmaf(hnew, wo[2][ntk], pv[r][2]);
                }
            }
            // keep the two halves' live ranges disjoint (reg-pressure fence)
            __builtin_amdgcn_sched_barrier(0);
        }

        // ---- v reduce over col: DPP rotate-adds (VALU pipe, no LDS) ----
#pragma unroll
        for (int r = 0; r < 4; ++r) {
            const unsigned p = q0 + (unsigned)(quad * 4 + r);
            const float pv0 = row16_sum(pv[r][0]);
            const float pv1 = row16_sum(pv[r][1]);
            const float pv2 = row16_sum(pv[r][2]);
            const float pvs = (col == 0) ? pv0 : ((col == 1) ? pv1 : pv2);
            if (col < 3)
                v_out[p * 3u + (unsigned)col] = fast_tanh(pvs + bo_sel);
        }
    }
#undef LOADA
}

extern "C" void kernel_launch(void* const* d_in, const int* in_sizes, int n_in,
                              void* d_out, int out_size, void* d_ws, size_t ws_size,
                              hipStream_t stream) {
    const float* h     = (const float*)d_in[0];
    const float* u     = (const float*)d_in[1];
    const float* W_h   = (const float*)d_in[2];
    const float* U_h   = (const float*)d_in[3];
    const float* b_h   = (const float*)d_in[4];
    const float* W_tau = (const float*)d_in[5];
    const float* U_tau = (const float*)d_in[6];
    const float* b_tau = (const float*)d_in[7];
    const float* W_out = (const float*)d_in[8];
    const float* b_out = (const float*)d_in[9];

    const int total = in_sizes[0] / HID;   // B*N positions (1048576)
    float* h_out = (float*)d_out;
    float* v_out = h_out + (size_t)total * HID;

    short* wbf = (short*)d_ws;   // 26624 B of scratch

    prep_weights<<<(WELEMS + 255) / 256, 256, 0, stream>>>(
        W_tau, U_tau, b_tau, W_h, U_h, b_h, wbf);

    const int ntiles = total / 64;   // 64 positions per block-tile
    // grid 768 = one balanced round at 3 blocks/CU (launch_bounds(256,3))
    const int grid = 768;
    liquid_mfma_kernel<<<grid, 256, 0, stream>>>(
        h, u, wbf, W_out, b_out, h_out, v_out, ntiles);
}